// Round 13
// baseline (25.393 us; speedup 1.0000x reference)
//
#include <hip/hip_runtime.h>

// YOLO loss forward, MI355X. Memory-bound streaming reduction.
// R13: BARRIER-FREE per-wave pipelines. Each wave owns a private LDS
//     triple-buffer (3 x 1920 floats) and stages/computes its own chunks;
//     the only sync is per-wave counted s_waitcnt vmcnt(16/8/0). No s_barrier
//     in the hot loop -> no 4-wave convoy per chunk (R12 showed barrier count
//     dominates). 1 block/CU (92.2 KB LDS), GRID=256.
//     Work map: wave (bid,wv) -> chunks bid + wv*256 + i*1024; the 256
//     remainder chunks land on wave 0 of EVERY block -> uniform per-CU load.
// LESSONS carried: (R6) global_load_lds writes in 16-lane groups -- active
//     lane count ≡ 0 (mod 16), contiguous from lane 0, within buffer.
//     (T4) per-wave vmcnt accounting: wave waits only on its OWN loads --
//     valid here because no wave reads another wave's staged data.
//     (R9/R11) no hipMemsetAsync nodes, no same-address atomic finish.
//     (R10) no cooperative grid.sync.

constexpr int N_IMG  = 2048;
constexpr int NC     = 30;
constexpr int CELLS  = N_IMG * 14 * 14;   // 401408
constexpr int BLOCK  = 256;
constexpr int CPW    = 32;                // cells per wave-chunk
constexpr int NCHT   = CELLS / CPW;       // 12544 total wave-chunks
constexpr int GRID   = 256;               // 1 block/CU
constexpr int WAVES  = GRID * 4;          // 1024 wave pipelines
constexpr float INV14 = 1.0f / 14.0f;

constexpr int FPW   = 2 * CPW * NC;       // floats per wave-buffer = 1920
constexpr int SLW   = FPW / 4;            // 480 float4 slots
constexpr int PREDW = CPW * NC / 4;       // 240 pred slots

__device__ __forceinline__ void gload16(const void* g, void* l) {
    __builtin_amdgcn_global_load_lds(
        (const __attribute__((address_space(1))) void*)g,
        (__attribute__((address_space(3))) void*)l, 16, 0, 0);
}

__device__ __forceinline__ float cell_loss(const float* __restrict__ cp,
                                           const float* __restrict__ ct)
{
    float pv[NC], tv[NC];
    const float2* p2 = reinterpret_cast<const float2*>(cp);  // 8B-aligned
    const float2* t2 = reinterpret_cast<const float2*>(ct);
    #pragma unroll
    for (int i = 0; i < NC / 2; ++i) {
        float2 a = p2[i]; pv[2*i] = a.x; pv[2*i+1] = a.y;
        float2 b = t2[i]; tv[2*i] = b.x; tv[2*i+1] = b.y;
    }

    const float coo = (tv[4] > 0.0f) ? 1.0f : 0.0f;

    const float txc = tv[0] * INV14, tyc = tv[1] * INV14;
    const float tx1 = txc - 0.5f * tv[2], ty1 = tyc - 0.5f * tv[3];
    const float tx2 = txc + 0.5f * tv[2], ty2 = tyc + 0.5f * tv[3];
    const float t_area = (tx2 - tx1) * (ty2 - ty1);

    float i0, u0;
    {
        const float xc = pv[0] * INV14, yc = pv[1] * INV14;
        const float x1 = xc - 0.5f * pv[2], y1 = yc - 0.5f * pv[3];
        const float x2 = xc + 0.5f * pv[2], y2 = yc + 0.5f * pv[3];
        const float a1 = (x2 - x1) * (y2 - y1);
        const float wx = fmaxf(fminf(x2, tx2) - fmaxf(x1, tx1), 0.0f);
        const float wy = fmaxf(fminf(y2, ty2) - fmaxf(y1, ty1), 0.0f);
        i0 = wx * wy;
        u0 = a1 + t_area - i0;            // > 0 (w,h >= 0.05)
    }
    float i1, u1;
    {
        const float xc = pv[5] * INV14, yc = pv[6] * INV14;
        const float x1 = xc - 0.5f * pv[7], y1 = yc - 0.5f * pv[8];
        const float x2 = xc + 0.5f * pv[7], y2 = yc + 0.5f * pv[8];
        const float a1 = (x2 - x1) * (y2 - y1);
        const float wx = fmaxf(fminf(x2, tx2) - fmaxf(x1, tx1), 0.0f);
        const float wy = fmaxf(fminf(y2, ty2) - fmaxf(y1, ty1), 0.0f);
        i1 = wx * wy;
        u1 = a1 + t_area - i1;
    }

    // argmax first-max tie-break, divide-free: iou1 > iou0 <=> i1*u0 > i0*u1
    const bool sel = (i1 * u0) > (i0 * u1);
    const float rp0 = sel ? pv[5] : pv[0];
    const float rp1 = sel ? pv[6] : pv[1];
    const float rp2 = sel ? pv[7] : pv[2];
    const float rp3 = sel ? pv[8] : pv[3];
    const float rp4 = sel ? pv[9] : pv[4];
    const float rt0 = sel ? tv[5] : tv[0];
    const float rt1 = sel ? tv[6] : tv[1];
    const float rt2 = sel ? tv[7] : tv[2];
    const float rt3 = sel ? tv[8] : tv[3];
    const float nrp4 = sel ? pv[4] : pv[9];

    const float d0 = rp0 - rt0, d1 = rp1 - rt1;
    const float d2 = sqrtf(rp2) - sqrtf(rt2);
    const float d3 = sqrtf(rp3) - sqrtf(rt3);
    const float loc     = d0*d0 + d1*d1 + d2*d2 + d3*d3;
    const float contain = rp4 * rp4;
    const float notc    = nrp4 * nrp4;
    const float e4 = pv[4] - tv[4], e9 = pv[9] - tv[9];
    const float noobj = e4*e4 + e9*e9;
    float cls = 0.0f;
    #pragma unroll
    for (int c = 10; c < NC; ++c) { const float d = pv[c] - tv[c]; cls += d*d; }

    return coo * (5.0f * loc + 2.0f * contain + notc + cls)
         + (1.0f - coo) * (0.5f * noobj);
}

__global__ __launch_bounds__(BLOCK)
void yolo_main(const float* __restrict__ pred,
               const float* __restrict__ targ,
               float* __restrict__ partial)
{
    // per-wave private triple buffers: [wave][buf][1920 floats]
    __shared__ float sbuf[4][3][FPW];     // 92160 B -> 1 block/CU

    const int tid = threadIdx.x;
    const int bid = blockIdx.x;
    const int wv  = tid >> 6;
    const int ln  = tid & 63;

    float* const wbase = &sbuf[wv][0][0];

    // stage one wave-chunk into this wave's buffer b: 7 full 64-lane rounds
    // + one 32-lane round (2 x 16-groups from lane 0 -- R6-safe).
    // 8 gloads per wave per stage; purely wave-private.
    auto stage = [&](int b, int chunk) {
        const size_t fb = (size_t)chunk * (size_t)(CPW * NC);
        const float4* gp = reinterpret_cast<const float4*>(pred + fb);
        const float4* gt = reinterpret_cast<const float4*>(targ + fb);
        float4* lb = reinterpret_cast<float4*>(wbase + b * FPW);
        #pragma unroll
        for (int i = 0; i < 7; ++i) {
            const int s = i * 64 + ln;
            gload16(s < PREDW ? gp + s : gt + (s - PREDW), lb + s);
        }
        if (ln < 32) {
            const int s = 448 + ln;       // 448..479: all targ
            gload16(gt + (s - PREDW), lb + s);
        }
    };

    const int g = bid + wv * 256;         // global wave id, [0,1024)
    const int n = (wv == 0) ? 13 : 12;    // 256 remainder chunks -> wave 0 of
                                          // every block: uniform per-CU load

    stage(0, g);
    stage(1, g + WAVES);

    float acc = 0.0f;
    for (int k = 0; k < n; ++k) {
        if (k + 2 < n) stage((k + 2) % 3, g + (k + 2) * WAVES);

        // certify chunk k (oldest 8 loads); keep later stages in flight.
        // lgkmcnt(0): order prior ds_reads vs in-flight DMA overwrites.
        if (k + 2 < n)
            asm volatile("s_waitcnt vmcnt(16) lgkmcnt(0)" ::: "memory");
        else if (k + 1 < n)
            asm volatile("s_waitcnt vmcnt(8) lgkmcnt(0)" ::: "memory");
        else
            asm volatile("s_waitcnt vmcnt(0) lgkmcnt(0)" ::: "memory");
        __builtin_amdgcn_sched_barrier(0);

        if (ln < CPW) {
            const float* b = wbase + (k % 3) * FPW;
            acc += cell_loss(b + ln * NC, b + CPW * NC + ln * NC);
        }
        __builtin_amdgcn_sched_barrier(0);   // next stage must not hoist
    }

    // block reduction (one-time barrier, outside the hot loop)
    __shared__ float wsum[BLOCK / 64];
    #pragma unroll
    for (int o = 32; o > 0; o >>= 1) acc += __shfl_down(acc, o, 64);
    if ((tid & 63) == 0) wsum[tid >> 6] = acc;
    __syncthreads();
    if (tid == 0)
        partial[bid] = wsum[0] + wsum[1] + wsum[2] + wsum[3];
}

__global__ __launch_bounds__(64)
void yolo_final(const float* __restrict__ partial, float* __restrict__ out)
{
    const int tid = threadIdx.x;
    double s = 0.0;
    #pragma unroll
    for (int i = 0; i < GRID / 64; ++i) s += (double)partial[tid + i * 64];
    #pragma unroll
    for (int o = 32; o > 0; o >>= 1) s += __shfl_down(s, o, 64);
    if (tid == 0) out[0] = (float)(s / (double)N_IMG);
}

extern "C" void kernel_launch(void* const* d_in, const int* in_sizes, int n_in,
                              void* d_out, int out_size, void* d_ws, size_t ws_size,
                              hipStream_t stream)
{
    const float* pred = (const float*)d_in[0];
    const float* targ = (const float*)d_in[1];
    float* out        = (float*)d_out;
    float* partial    = (float*)d_ws;   // 256 floats = 1 KB

    yolo_main<<<GRID, BLOCK, 0, stream>>>(pred, targ, partial);
    yolo_final<<<1, 64, 0, stream>>>(partial, out);
}

// Round 14
// 22.686 us; speedup vs baseline: 1.1193x; 1.1193x over previous
//
#include <hip/hip_runtime.h>

// YOLO loss forward, MI355X. Memory-bound streaming reduction.
// FINAL (= R8, best of 13 rounds, 22.66 us): 3-deep counted-vmcnt pipeline
//     (T3/T4, m218 technique, plain HIP): raw s_barrier + manual s_waitcnt
//     vmcnt(4) -- prefetch of chunk k+2 stays in flight ACROSS the barrier;
//     only chunk k+1 is certified complete. CPB=64, 3 buffers x 15.36 KB =
//     46 KB -> 3 blocks/CU. GRID=768, grid-stride over 6272 chunks.
//     Two-dispatch finish (partials + 64-thread final kernel): measured best
//     vs atomicAdd finish (+10us, serialized same-address tail), memset node
//     (+10us), cooperative grid.sync (+85us).
// Ceiling arithmetic: 96.3 MB stream @ ~6.3 TB/s = 15.3 us + ~5-7 us fixed
//     graph/dispatch overhead (empirically immovable) ~= 21-22 us practical
//     floor; five structural families cluster at 22.7-25.4 with this best.
// LESSONS: (R6) global_load_lds writes in 16-lane groups -- active lane count
//     must be ≡0 (mod 16), contiguous from lane 0, within the dest buffer.
//     (T4) every wave issues the SAME gload count per stage so vmcnt(N) means
//     the same thing in every wave.

constexpr int N_IMG  = 2048;
constexpr int NC     = 30;
constexpr int CELLS  = N_IMG * 14 * 14;   // 401408
constexpr int BLOCK  = 256;
constexpr int CPB    = 64;                // cells per chunk
constexpr int NCHT   = CELLS / CPB;       // 6272 total chunks
constexpr int GRID   = 768;               // 3 blocks/CU (46 KB LDS each)
constexpr float INV14 = 1.0f / 14.0f;

constexpr int FPB   = 2 * CPB * NC;       // floats per buffer (pred+targ) = 3840
constexpr int SLOTS = FPB / 4;            // 960 float4 slots per buffer
constexpr int SPW   = SLOTS / 4;          // 240 slots per wave
constexpr int PREDS = CPB * NC / 4;       // 480 pred slots

__device__ __forceinline__ void gload16(const void* g, void* l) {
    __builtin_amdgcn_global_load_lds(
        (const __attribute__((address_space(1))) void*)g,
        (__attribute__((address_space(3))) void*)l, 16, 0, 0);
}

__device__ __forceinline__ float cell_loss(const float* __restrict__ cp,
                                           const float* __restrict__ ct)
{
    float pv[NC], tv[NC];
    const float2* p2 = reinterpret_cast<const float2*>(cp);  // 8B-aligned
    const float2* t2 = reinterpret_cast<const float2*>(ct);
    #pragma unroll
    for (int i = 0; i < NC / 2; ++i) {
        float2 a = p2[i]; pv[2*i] = a.x; pv[2*i+1] = a.y;
        float2 b = t2[i]; tv[2*i] = b.x; tv[2*i+1] = b.y;
    }

    const float coo = (tv[4] > 0.0f) ? 1.0f : 0.0f;

    const float txc = tv[0] * INV14, tyc = tv[1] * INV14;
    const float tx1 = txc - 0.5f * tv[2], ty1 = tyc - 0.5f * tv[3];
    const float tx2 = txc + 0.5f * tv[2], ty2 = tyc + 0.5f * tv[3];
    const float t_area = (tx2 - tx1) * (ty2 - ty1);

    float i0, u0;
    {
        const float xc = pv[0] * INV14, yc = pv[1] * INV14;
        const float x1 = xc - 0.5f * pv[2], y1 = yc - 0.5f * pv[3];
        const float x2 = xc + 0.5f * pv[2], y2 = yc + 0.5f * pv[3];
        const float a1 = (x2 - x1) * (y2 - y1);
        const float wx = fmaxf(fminf(x2, tx2) - fmaxf(x1, tx1), 0.0f);
        const float wy = fmaxf(fminf(y2, ty2) - fmaxf(y1, ty1), 0.0f);
        i0 = wx * wy;
        u0 = a1 + t_area - i0;            // > 0 (w,h >= 0.05)
    }
    float i1, u1;
    {
        const float xc = pv[5] * INV14, yc = pv[6] * INV14;
        const float x1 = xc - 0.5f * pv[7], y1 = yc - 0.5f * pv[8];
        const float x2 = xc + 0.5f * pv[7], y2 = yc + 0.5f * pv[8];
        const float a1 = (x2 - x1) * (y2 - y1);
        const float wx = fmaxf(fminf(x2, tx2) - fmaxf(x1, tx1), 0.0f);
        const float wy = fmaxf(fminf(y2, ty2) - fmaxf(y1, ty1), 0.0f);
        i1 = wx * wy;
        u1 = a1 + t_area - i1;
    }

    // argmax first-max tie-break, divide-free: iou1 > iou0 <=> i1*u0 > i0*u1
    const bool sel = (i1 * u0) > (i0 * u1);
    const float rp0 = sel ? pv[5] : pv[0];
    const float rp1 = sel ? pv[6] : pv[1];
    const float rp2 = sel ? pv[7] : pv[2];
    const float rp3 = sel ? pv[8] : pv[3];
    const float rp4 = sel ? pv[9] : pv[4];
    const float rt0 = sel ? tv[5] : tv[0];
    const float rt1 = sel ? tv[6] : tv[1];
    const float rt2 = sel ? tv[7] : tv[2];
    const float rt3 = sel ? tv[8] : tv[3];
    const float nrp4 = sel ? pv[4] : pv[9];

    const float d0 = rp0 - rt0, d1 = rp1 - rt1;
    const float d2 = sqrtf(rp2) - sqrtf(rt2);
    const float d3 = sqrtf(rp3) - sqrtf(rt3);
    const float loc     = d0*d0 + d1*d1 + d2*d2 + d3*d3;
    const float contain = rp4 * rp4;
    const float notc    = nrp4 * nrp4;
    const float e4 = pv[4] - tv[4], e9 = pv[9] - tv[9];
    const float noobj = e4*e4 + e9*e9;
    float cls = 0.0f;
    #pragma unroll
    for (int c = 10; c < NC; ++c) { const float d = pv[c] - tv[c]; cls += d*d; }

    return coo * (5.0f * loc + 2.0f * contain + notc + cls)
         + (1.0f - coo) * (0.5f * noobj);
}

__global__ __launch_bounds__(BLOCK)
void yolo_main(const float* __restrict__ pred,
               const float* __restrict__ targ,
               float* __restrict__ partial)
{
    // buffer layout: floats [0,1920) = pred chunk, [1920,3840) = targ chunk
    __shared__ float sbuf[3 * FPB];       // 3 x 15360 B = 46 KB -> 3 blocks/CU

    const int tid = threadIdx.x;
    const int bid = blockIdx.x;
    const int wv  = tid >> 6;
    const int ln  = tid & 63;

    // stage chunk into lbuf. Per-wave contiguous 240-slot segment:
    // 3 full 64-lane rounds + one 48-lane round (3 x 16-groups from lane 0).
    // EVERY wave issues exactly 4 gloads -> uniform vmcnt accounting.
    auto stage = [&](float* lbuf, int chunk) {
        const size_t fbase = (size_t)chunk * (size_t)(CPB * NC);
        const int wbase = wv * SPW;       // 0,240,480,720
        const float4* gsrc = (wv < 2)
            ? reinterpret_cast<const float4*>(pred + fbase) + wbase
            : reinterpret_cast<const float4*>(targ + fbase) + (wbase - PREDS);
        float4* lb = reinterpret_cast<float4*>(lbuf) + wbase;
        #pragma unroll
        for (int i = 0; i < 3; ++i)
            gload16(gsrc + i * 64 + ln, lb + i * 64 + ln);
        if (ln < 48)
            gload16(gsrc + 192 + ln, lb + 192 + ln);
    };

    const int n = (NCHT - bid + GRID - 1) / GRID;   // 9 (bid<128) or 8

    // prologue: fill buffers 0,1 (8 outstanding); wait oldest 4 -> buf0 ready
    stage(sbuf, bid);
    stage(sbuf + FPB, bid + GRID);
    asm volatile("s_waitcnt vmcnt(4)" ::: "memory");
    __builtin_amdgcn_sched_barrier(0);
    __builtin_amdgcn_s_barrier();
    __builtin_amdgcn_sched_barrier(0);

    float acc = 0.0f;
    for (int k = 0; k < n; ++k) {
        const bool pre = (k + 2 < n);
        if (pre) stage(sbuf + ((k + 2) % 3) * FPB, bid + (k + 2) * GRID);

        if (tid < CPB) {
            const float* b = sbuf + (k % 3) * FPB;
            acc += cell_loss(b + tid * NC, b + CPB * NC + tid * NC);
        }

        // certify buf[k+1] complete; keep buf[k+2]'s 4 loads in flight
        if (pre) asm volatile("s_waitcnt vmcnt(4)" ::: "memory");
        else     asm volatile("s_waitcnt vmcnt(0)" ::: "memory");
        __builtin_amdgcn_sched_barrier(0);
        __builtin_amdgcn_s_barrier();
        __builtin_amdgcn_sched_barrier(0);
    }

    // block reduction
    __shared__ float wsum[BLOCK / 64];
    #pragma unroll
    for (int o = 32; o > 0; o >>= 1) acc += __shfl_down(acc, o, 64);
    if ((tid & 63) == 0) wsum[tid >> 6] = acc;
    __syncthreads();
    if (tid == 0)
        partial[bid] = wsum[0] + wsum[1] + wsum[2] + wsum[3];
}

__global__ __launch_bounds__(64)
void yolo_final(const float* __restrict__ partial, float* __restrict__ out)
{
    const int tid = threadIdx.x;
    double s = 0.0;
    #pragma unroll
    for (int i = 0; i < GRID / 64; ++i) s += (double)partial[tid + i * 64];
    #pragma unroll
    for (int o = 32; o > 0; o >>= 1) s += __shfl_down(s, o, 64);
    if (tid == 0) out[0] = (float)(s / (double)N_IMG);
}

extern "C" void kernel_launch(void* const* d_in, const int* in_sizes, int n_in,
                              void* d_out, int out_size, void* d_ws, size_t ws_size,
                              hipStream_t stream)
{
    const float* pred = (const float*)d_in[0];
    const float* targ = (const float*)d_in[1];
    float* out        = (float*)d_out;
    float* partial    = (float*)d_ws;   // 768 floats = 3 KB

    yolo_main<<<GRID, BLOCK, 0, stream>>>(pred, targ, partial);
    yolo_final<<<1, 64, 0, stream>>>(partial, out);
}